// Round 1
// baseline (393.088 us; speedup 1.0000x reference)
//
#include <hip/hip_runtime.h>
#include <math.h>

// Problem constants (match reference)
#define T_LEN 4096
#define FIR_L 513
#define N_PHA 10
#define N_AMP 10
#define N_BANDS 20
#define N_BINS 18
#define BC 64            // B*C = 4*16

// ---------------------------------------------------------------------------
// Kernel 1: per (bc, band): FIR bandpass (time domain, 'same' zero-pad) then
// FFT-based Hilbert analytic signal (DIF fwd -> mask -> DIT inv, all in LDS),
// emit phase (bands 0..9) or amplitude (bands 10..19) to workspace.
// ---------------------------------------------------------------------------
__global__ __launch_bounds__(256) void conv_hilbert_kernel(
    const float* __restrict__ x,      // (BC, T)
    const float* __restrict__ filt,   // (20, 513)
    float* __restrict__ pha,          // (BC, 10, T)
    float* __restrict__ amp)          // (BC, 10, T)
{
    // smem layout:
    //   [0 .. 4608)      : padded x row (conv phase)   -- later re[0..4096)
    //   [4096 .. 8192)   : im[]
    //   [8192 .. 10240)  : twiddle cos table (2048)
    //   [10240 .. 12288) : twiddle sin table (2048)
    __shared__ float smem[12288];
    __shared__ float fs[FIR_L];

    float* xsp = smem;            // 4608 floats during conv
    float* re  = smem;            // 4096 floats during FFT
    float* im  = smem + 4096;
    float* twc = smem + 8192;
    float* tws = smem + 8192 + 2048;

    const int tid  = threadIdx.x;
    const int bc   = blockIdx.x / N_BANDS;
    const int band = blockIdx.x % N_BANDS;

    // Twiddle tables: exp(-i*2*pi*m/4096) stored as (cos, sin) of theta=2pi*m/4096
    for (int m = tid; m < 2048; m += 256) {
        float ang = (float)m * (6.283185307179586f / 4096.0f);
        float s, c;
        sincosf(ang, &s, &c);
        twc[m] = c;
        tws[m] = s;
    }

    // Load padded input row: xsp[i] = x[bc][i-256], zeros outside [0,T)
    const float* xrow = x + bc * T_LEN;
    for (int i = tid; i < 4608; i += 256) {
        int src = i - 256;
        xsp[i] = (src >= 0 && src < T_LEN) ? xrow[src] : 0.0f;
    }
    for (int i = tid; i < FIR_L; i += 256) fs[i] = filt[band * FIR_L + i];
    __syncthreads();

    // ---- Direct conv: out[t] = sum_l x[t-256+l]*f[l] == sum_l xsp[t+l]*f[l]
    // Thread handles t0..t0+15 contiguous; rolling 16-register window: the
    // slot (l+j)&15 holds xsp[t0+l+j] at tap l.
    const int t0 = tid * 16;
    float acc[16];
    float v[16];
#pragma unroll
    for (int j = 0; j < 16; ++j) acc[j] = 0.0f;
#pragma unroll
    for (int j = 0; j < 16; ++j) v[j] = xsp[t0 + j];

    for (int lb = 0; lb < 512; lb += 16) {
#pragma unroll
        for (int u = 0; u < 16; ++u) {
            const int l = lb + u;
            const float f = fs[l];
#pragma unroll
            for (int j = 0; j < 16; ++j)
                acc[j] = fmaf(f, v[(u + j) & 15], acc[j]);
            v[u] = xsp[t0 + l + 16];   // value needed at tap l+16
        }
    }
    {   // last tap l = 512; slot (512+j)&15 == j
        const float f = fs[512];
#pragma unroll
        for (int j = 0; j < 16; ++j)
            acc[j] = fmaf(f, v[j], acc[j]);
    }
    __syncthreads();   // all conv reads of xsp done before aliasing as re[]

    // ---- Write filtered signal as complex (re, 0)
#pragma unroll
    for (int j = 0; j < 16; ++j) {
        re[t0 + j] = acc[j];
        im[t0 + j] = 0.0f;
    }
    __syncthreads();

    // ---- Forward FFT, DIF (Gentleman-Sande): natural in -> bit-reversed out
    for (int st = 11; st >= 0; --st) {
        const int h = 1 << st;
#pragma unroll 1
        for (int u = tid; u < 2048; u += 256) {
            const int k  = u & (h - 1);
            const int g  = u >> st;
            const int i  = (g << (st + 1)) + k;
            const int jj = i + h;
            const int m  = k << (11 - st);
            const float c = twc[m], s = tws[m];   // w = c - i*s
            float ar = re[i], ai = im[i], br = re[jj], bi = im[jj];
            re[i] = ar + br;
            im[i] = ai + bi;
            float tr = ar - br, ti = ai - bi;
            re[jj] = fmaf(tr, c,  ti * s);   // (tr+i*ti)*(c-i*s)
            im[jj] = fmaf(ti, c, -tr * s);
        }
        __syncthreads();
    }

    // ---- Hilbert mask (data is in bit-reversed order; freq = brev12(i))
    for (int i = tid; i < 4096; i += 256) {
        const int k = (int)(__brev((unsigned)i) >> 20);
        float mfac = (k == 0 || k == 2048) ? 1.0f : (k < 2048 ? 2.0f : 0.0f);
        re[i] *= mfac;
        im[i] *= mfac;
    }
    __syncthreads();

    // ---- Inverse FFT, DIT: bit-reversed in -> natural out (scale 1/N later)
    for (int st = 0; st <= 11; ++st) {
        const int h = 1 << st;
#pragma unroll 1
        for (int u = tid; u < 2048; u += 256) {
            const int k  = u & (h - 1);
            const int g  = u >> st;
            const int i  = (g << (st + 1)) + k;
            const int jj = i + h;
            const int m  = k << (11 - st);
            const float c = twc[m], s = tws[m];   // w = c + i*s
            float br = re[jj], bi = im[jj];
            float tr = fmaf(br, c, -bi * s);      // (br+i*bi)*(c+i*s)
            float ti = fmaf(br, s,  bi * c);
            float ar = re[i], ai = im[i];
            re[i]  = ar + tr;
            im[i]  = ai + ti;
            re[jj] = ar - tr;
            im[jj] = ai - ti;
        }
        __syncthreads();
    }

    // ---- Emit phase or amplitude
    const float inv_n = 1.0f / 4096.0f;
    if (band < N_PHA) {
        float* dst = pha + (bc * N_PHA + band) * T_LEN;
        for (int i = tid; i < 4096; i += 256)
            dst[i] = atan2f(im[i], re[i]);       // scale cancels in atan2
    } else {
        float* dst = amp + (bc * N_AMP + (band - N_PHA)) * T_LEN;
        for (int i = tid; i < 4096; i += 256)
            dst[i] = sqrtf(re[i] * re[i] + im[i] * im[i]) * inv_n;
    }
}

// ---------------------------------------------------------------------------
// Kernel 2: per (bc, pha-band): soft phase binning + mean-amp per bin per amp
// band + Tort MI.  256-sample t-tiles; weights staged in LDS; 180 threads own
// one (a,k) accumulator, 18 threads own cnt[k]; 10 threads finish MI.
// ---------------------------------------------------------------------------
__global__ __launch_bounds__(256) void bin_mi_kernel(
    const float* __restrict__ pha,    // (BC, 10, T)
    const float* __restrict__ amp,    // (BC, 10, T)
    float* __restrict__ out)          // (BC, 10, 10)
{
    const int tid = threadIdx.x;
    const int bc  = blockIdx.x / N_PHA;
    const int p   = blockIdx.x % N_PHA;

    __shared__ float wtile[256 * N_BINS];   // [tt][k]
    __shared__ float atile[N_AMP * 256];    // [a][tt]
    __shared__ float asumL[N_AMP * N_BINS];
    __shared__ float cntL[N_BINS];

    const int a_ = tid / N_BINS;   // valid for tid < 180
    const int k_ = tid % N_BINS;

    float accA = 0.0f;   // amp_sum(a_,k_)
    float accC = 0.0f;   // cnt(k) for tid in [180,198)

    const float* phrow  = pha + (bc * N_PHA + p) * T_LEN;
    const float* amprow = amp + bc * N_AMP * T_LEN;

    const float PI_F   = 3.14159274101257324f;   // float32(np.pi)
    const float TWOPI  = 6.28318548202514648f;   // float32(2*np.pi)

    for (int t0 = 0; t0 < T_LEN; t0 += 256) {
        // stage amplitude tile (coalesced)
#pragma unroll
        for (int a = 0; a < N_AMP; ++a)
            atile[a * 256 + tid] = amprow[a * T_LEN + t0 + tid];

        // this thread's sample -> 18 softmax weights
        const float ph = phrow[t0 + tid];
        float logit[N_BINS];
        float mx = -1e30f;
#pragma unroll
        for (int k = 0; k < N_BINS; ++k) {
            // center computed in double at compile time, rounded to f32
            const float center =
                (float)(-3.141592653589793 + 6.283185307179586 * (k + 0.5) / 18.0);
            float d0 = ph - center + PI_F;
            float r  = fmodf(d0, TWOPI);         // jnp.mod semantics for y>0
            if (r < 0.0f) r += TWOPI;
            float d  = r - PI_F;
            float lg = -(d * d) / 0.01f;
            logit[k] = lg;
            mx = fmaxf(mx, lg);
        }
        float ssum = 0.0f;
#pragma unroll
        for (int k = 0; k < N_BINS; ++k) {
            float e = expf(logit[k] - mx);
            logit[k] = e;
            ssum += e;
        }
        const float inv = 1.0f / ssum;
#pragma unroll
        for (int k = 0; k < N_BINS; ++k)
            wtile[tid * N_BINS + k] = logit[k] * inv;
        __syncthreads();

        // accumulate over the 256-sample tile
        if (tid < 180) {
            const float* wt = wtile + k_;
            const float* at = atile + a_ * 256;
#pragma unroll 4
            for (int tt = 0; tt < 256; ++tt)
                accA = fmaf(wt[tt * N_BINS], at[tt], accA);
        } else if (tid < 180 + N_BINS) {
            const int kk = tid - 180;
            const float* wt = wtile + kk;
#pragma unroll 4
            for (int tt = 0; tt < 256; ++tt)
                accC += wt[tt * N_BINS];
        }
        __syncthreads();
    }

    if (tid < 180) asumL[tid] = accA;
    if (tid >= 180 && tid < 180 + N_BINS) cntL[tid - 180] = accC;
    __syncthreads();

    if (tid < N_AMP) {
        float ma[N_BINS];
        float msum = 0.0f;
#pragma unroll
        for (int k = 0; k < N_BINS; ++k) {
            float m = asumL[tid * N_BINS + k] / (cntL[k] + 1e-8f);
            ma[k] = m;
            msum += m;
        }
        const float inv = 1.0f / (msum + 1e-8f);
        float acc = 0.0f;
#pragma unroll
        for (int k = 0; k < N_BINS; ++k) {
            float pk = ma[k] * inv;
            acc = fmaf(pk, logf(pk + 1e-8f), acc);
        }
        const float logk = 2.89037175789124f;    // log(18)
        out[(bc * N_PHA + p) * N_AMP + tid] = (logk + acc) / logk;
    }
}

extern "C" void kernel_launch(void* const* d_in, const int* in_sizes, int n_in,
                              void* d_out, int out_size, void* d_ws, size_t ws_size,
                              hipStream_t stream) {
    const float* x    = (const float*)d_in[0];   // (4,16,4096) f32
    const float* filt = (const float*)d_in[1];   // (20,513) f32
    float* out = (float*)d_out;                  // (4,16,10,10) f32

    float* pha = (float*)d_ws;                   // BC*10*T floats
    float* amp = pha + BC * N_PHA * T_LEN;       // BC*10*T floats

    conv_hilbert_kernel<<<BC * N_BANDS, 256, 0, stream>>>(x, filt, pha, amp);
    bin_mi_kernel<<<BC * N_PHA, 256, 0, stream>>>(pha, amp, out);
}

// Round 2
// 304.759 us; speedup vs baseline: 1.2898x; 1.2898x over previous
//
#include <hip/hip_runtime.h>
#include <math.h>

// Problem constants (match reference)
#define T_LEN 4096
#define FIR_L 513
#define N_PHA 10
#define N_AMP 10
#define N_BANDS 20
#define N_BINS 18
#define BC 64            // B*C = 4*16

typedef __attribute__((ext_vector_type(8))) short short8;
typedef __attribute__((ext_vector_type(4))) float f32x4;

// Skewed LDS index: breaks the lane-stride-16 (64B) bank pattern.
// addr(i) = i + i/32 -> stride-16 lane accesses hit all 32 banks 2-way (free).
#define SK(i) ((i) + ((i) >> 5))

// float -> bf16 round-to-nearest-even
static __device__ __forceinline__ unsigned short f2bf(float x) {
    unsigned u = __float_as_uint(x);
    unsigned r = u + 0x7FFFu + ((u >> 16) & 1u);
    return (unsigned short)(r >> 16);
}

// ---------------------------------------------------------------------------
// Kernel 1: per (bc, band): FIR bandpass (time domain, 'same' zero-pad) then
// FFT-based Hilbert analytic signal (DIF fwd -> mask -> DIT inv, all in LDS),
// emit phase fp32 (bands 0..9) or amplitude bf16 (bands 10..19).
// ---------------------------------------------------------------------------
__global__ __launch_bounds__(256) void conv_hilbert_kernel(
    const float* __restrict__ x,          // (BC, T)
    const float* __restrict__ filt,       // (20, 513)
    float* __restrict__ pha,              // (BC, 10, T) fp32
    unsigned short* __restrict__ amp_bf)  // (BC, 10, T) bf16 bits
{
    // smem layout:
    //   [0 .. ~4750)     : skewed padded x row (conv phase)  -- later re[0..4096)
    //   [4096 .. 8192)   : im[]
    //   [8192 .. 10240)  : twiddle cos table (2048)
    //   [10240 .. 12288) : twiddle sin table (2048)
    __shared__ float smem[12288];
    __shared__ float fs[FIR_L + 3];   // pad for float4 reads

    float* xsp = smem;            // skewed indices, up to SK(4607)=4750 < 8192
    float* re  = smem;
    float* im  = smem + 4096;
    float* twc = smem + 8192;
    float* tws = smem + 8192 + 2048;

    const int tid  = threadIdx.x;
    const int bc   = blockIdx.x / N_BANDS;
    const int band = blockIdx.x % N_BANDS;

    for (int m = tid; m < 2048; m += 256) {
        float ang = (float)m * (6.283185307179586f / 4096.0f);
        float s, c;
        sincosf(ang, &s, &c);
        twc[m] = c;
        tws[m] = s;
    }

    // Load padded input row (skewed): xsp[SK(i)] = x[bc][i-256], zeros outside
    const float* xrow = x + bc * T_LEN;
    for (int i = tid; i < 4608; i += 256) {
        int src = i - 256;
        xsp[SK(i)] = (src >= 0 && src < T_LEN) ? xrow[src] : 0.0f;
    }
    for (int i = tid; i < FIR_L; i += 256) fs[i] = filt[band * FIR_L + i];
    if (tid < 3) fs[FIR_L + tid] = 0.0f;
    __syncthreads();

    // ---- Direct conv, rolling 16-register window, skewed LDS reads
    const int t0 = tid * 16;
    float acc[16];
    float v[16];
#pragma unroll
    for (int j = 0; j < 16; ++j) acc[j] = 0.0f;
#pragma unroll
    for (int j = 0; j < 16; ++j) v[j] = xsp[SK(t0 + j)];

    for (int lb = 0; lb < 512; lb += 16) {
#pragma unroll
        for (int u4 = 0; u4 < 4; ++u4) {
            const float4 fq = *(const float4*)&fs[lb + u4 * 4];
#pragma unroll
            for (int s = 0; s < 4; ++s) {
                const int u = u4 * 4 + s;
                const int l = lb + u;
                const float f = (s == 0) ? fq.x : (s == 1) ? fq.y : (s == 2) ? fq.z : fq.w;
#pragma unroll
                for (int j = 0; j < 16; ++j)
                    acc[j] = fmaf(f, v[(u + j) & 15], acc[j]);
                v[u] = xsp[SK(t0 + l + 16)];
            }
        }
    }
    {   // last tap l = 512; slot (512+j)&15 == j
        const float f = fs[512];
#pragma unroll
        for (int j = 0; j < 16; ++j)
            acc[j] = fmaf(f, v[j], acc[j]);
    }
    __syncthreads();   // all conv reads of xsp done before aliasing as re[]

#pragma unroll
    for (int j = 0; j < 16; ++j) {
        re[t0 + j] = acc[j];
        im[t0 + j] = 0.0f;
    }
    __syncthreads();

    // ---- Forward FFT, DIF: natural in -> bit-reversed out
    for (int st = 11; st >= 0; --st) {
        const int h = 1 << st;
#pragma unroll 1
        for (int u = tid; u < 2048; u += 256) {
            const int k  = u & (h - 1);
            const int g  = u >> st;
            const int i  = (g << (st + 1)) + k;
            const int jj = i + h;
            const int m  = k << (11 - st);
            const float c = twc[m], s = tws[m];   // w = c - i*s
            float ar = re[i], ai = im[i], br = re[jj], bi = im[jj];
            re[i] = ar + br;
            im[i] = ai + bi;
            float tr = ar - br, ti = ai - bi;
            re[jj] = fmaf(tr, c,  ti * s);
            im[jj] = fmaf(ti, c, -tr * s);
        }
        __syncthreads();
    }

    // ---- Hilbert mask (bit-reversed order; freq = brev12(i))
    for (int i = tid; i < 4096; i += 256) {
        const int k = (int)(__brev((unsigned)i) >> 20);
        float mfac = (k == 0 || k == 2048) ? 1.0f : (k < 2048 ? 2.0f : 0.0f);
        re[i] *= mfac;
        im[i] *= mfac;
    }
    __syncthreads();

    // ---- Inverse FFT, DIT: bit-reversed in -> natural out
    for (int st = 0; st <= 11; ++st) {
        const int h = 1 << st;
#pragma unroll 1
        for (int u = tid; u < 2048; u += 256) {
            const int k  = u & (h - 1);
            const int g  = u >> st;
            const int i  = (g << (st + 1)) + k;
            const int jj = i + h;
            const int m  = k << (11 - st);
            const float c = twc[m], s = tws[m];   // w = c + i*s
            float br = re[jj], bi = im[jj];
            float tr = fmaf(br, c, -bi * s);
            float ti = fmaf(br, s,  bi * c);
            float ar = re[i], ai = im[i];
            re[i]  = ar + tr;
            im[i]  = ai + ti;
            re[jj] = ar - tr;
            im[jj] = ar != ar ? 0.0f : ai - ti;   // (keep simple: ai - ti)
        }
        __syncthreads();
    }

    // ---- Emit phase (fp32) or amplitude (bf16)
    const float inv_n = 1.0f / 4096.0f;
    if (band < N_PHA) {
        float* dst = pha + (bc * N_PHA + band) * T_LEN;
        for (int i = tid; i < 4096; i += 256)
            dst[i] = atan2f(im[i], re[i]);       // scale cancels in atan2
    } else {
        unsigned short* dst = amp_bf + (bc * N_AMP + (band - N_PHA)) * T_LEN;
        for (int i = tid; i < 4096; i += 256)
            dst[i] = f2bf(sqrtf(re[i] * re[i] + im[i] * im[i]) * inv_n);
    }
}

// ---------------------------------------------------------------------------
// Kernel 2: per (bc, pha-band): soft phase binning + einsum via MFMA + MI.
// GEMM view: amp_sum[a][k] = sum_t A[a][t] * w[t][k], A row 10 = ones -> cnt.
// mfma_f32_16x16x32_bf16, M-tile: 16 rows (11 used), N-tiles: bins 0-15, 16-17.
// 4 waves split K=4096; LDS reduce; MI on 10 threads.
// ---------------------------------------------------------------------------
__global__ __launch_bounds__(256) void bin_mi_mfma(
    const float* __restrict__ pha,             // (BC, 10, T) fp32
    const unsigned short* __restrict__ amp_bf, // (BC, 10, T) bf16 bits
    float* __restrict__ out)                   // (BC, 10, 10)
{
    const int tid  = threadIdx.x;
    const int lane = tid & 63;
    const int wv   = tid >> 6;        // 0..3
    const int bc   = blockIdx.x / N_PHA;
    const int p    = blockIdx.x % N_PHA;

    // per-wave w buffer: 18 rows x 68 words (136 bf16, chunk=128 samples + pad)
    __shared__ unsigned int wbufW[4][18 * 68];
    __shared__ float psum[4][11][N_BINS];
    __shared__ float asum[11][N_BINS];

    const float* phrow = pha + (bc * N_PHA + p) * T_LEN;
    const unsigned short* arow = amp_bf + bc * N_AMP * T_LEN;

    const float PI_F  = 3.14159274101257324f;
    const float TWOPI = 6.28318548202514648f;

    const int m_ = lane & 15;         // A row / C row-group base
    const int q_ = lane >> 4;         // 0..3
    const int n_ = lane & 15;         // B col (bin)

    short8 zero8;
#pragma unroll
    for (int j = 0; j < 8; ++j) zero8[j] = 0;
    short8 ones8;
#pragma unroll
    for (int j = 0; j < 8; ++j) ones8[j] = (short)0x3F80;   // bf16 1.0

    f32x4 acc0 = {0.f, 0.f, 0.f, 0.f};   // bins 0..15
    f32x4 acc1 = {0.f, 0.f, 0.f, 0.f};   // bins 16..17 (cols 0,1)

    const int base_t = wv * 1024;

    for (int chunk = 0; chunk < 8; ++chunk) {
        const int cb = base_t + chunk * 128;

        // ---- compute w for 2 samples per lane, store packed bf16 transposed
        const int ts = cb + lane * 2;
        const float ph0 = phrow[ts];
        const float ph1 = phrow[ts + 1];
        float w0[N_BINS], w1[N_BINS];
        {
            float mx0 = -1e30f, mx1 = -1e30f;
#pragma unroll
            for (int k = 0; k < N_BINS; ++k) {
                const float center =
                    (float)(-3.141592653589793 + 6.283185307179586 * (k + 0.5) / 18.0);
                float d0 = ph0 - center + PI_F;
                float r0 = fmodf(d0, TWOPI); if (r0 < 0.0f) r0 += TWOPI;
                float dd0 = r0 - PI_F;
                float lg0 = -(dd0 * dd0) / 0.01f;
                w0[k] = lg0; mx0 = fmaxf(mx0, lg0);
                float d1 = ph1 - center + PI_F;
                float r1 = fmodf(d1, TWOPI); if (r1 < 0.0f) r1 += TWOPI;
                float dd1 = r1 - PI_F;
                float lg1 = -(dd1 * dd1) / 0.01f;
                w1[k] = lg1; mx1 = fmaxf(mx1, lg1);
            }
            float s0 = 0.0f, s1 = 0.0f;
#pragma unroll
            for (int k = 0; k < N_BINS; ++k) {
                float e0 = expf(w0[k] - mx0); w0[k] = e0; s0 += e0;
                float e1 = expf(w1[k] - mx1); w1[k] = e1; s1 += e1;
            }
            const float i0 = 1.0f / s0, i1 = 1.0f / s1;
#pragma unroll
            for (int k = 0; k < N_BINS; ++k) {
                unsigned int pk = (unsigned int)f2bf(w0[k] * i0)
                                | ((unsigned int)f2bf(w1[k] * i1) << 16);
                wbufW[wv][k * 68 + lane] = pk;
            }
        }
        __syncthreads();

        // ---- 4 MFMA K-steps (K=32 each) over this 128-sample chunk
#pragma unroll
        for (int s = 0; s < 4; ++s) {
            const int tA = cb + s * 32 + q_ * 8;
            // A fragment: rows 0..9 amp, row 10 ones (-> cnt), 11..15 zero
            short8 afrag;
            if (m_ < N_AMP) {
                afrag = *(const short8*)(arow + m_ * T_LEN + tA);
            } else if (m_ == N_AMP) {
                afrag = ones8;
            } else {
                afrag = zero8;
            }
            // B fragment 0: bins 0..15
            const int woff = s * 16 + q_ * 4;
            short8 bfrag0 = *(const short8*)&wbufW[wv][n_ * 68 + woff];
            // B fragment 1: bins 16,17 in cols 0,1
            short8 bfrag1 = (n_ < 2)
                ? *(const short8*)&wbufW[wv][(16 + n_) * 68 + woff]
                : zero8;
            acc0 = __builtin_amdgcn_mfma_f32_16x16x32_bf16(afrag, bfrag0, acc0, 0, 0, 0);
            acc1 = __builtin_amdgcn_mfma_f32_16x16x32_bf16(afrag, bfrag1, acc1, 0, 0, 0);
        }
        __syncthreads();   // protect wbufW before next chunk's writes
    }

    // ---- write per-wave C tiles to LDS (C/D: col=lane&15, row=(lane>>4)*4+reg)
#pragma unroll
    for (int r = 0; r < 4; ++r) {
        const int m = q_ * 4 + r;
        if (m < 11) {
            psum[wv][m][n_] = acc0[r];
            if (n_ < 2) psum[wv][m][16 + n_] = acc1[r];
        }
    }
    __syncthreads();

    // ---- reduce 4 waves
    if (tid < 11 * N_BINS) {
        const int m = tid / N_BINS;
        const int k = tid % N_BINS;
        asum[m][k] = psum[0][m][k] + psum[1][m][k] + psum[2][m][k] + psum[3][m][k];
    }
    __syncthreads();

    // ---- MI per amp band
    if (tid < N_AMP) {
        float ma[N_BINS];
        float msum = 0.0f;
#pragma unroll
        for (int k = 0; k < N_BINS; ++k) {
            float m = asum[tid][k] / (asum[10][k] + 1e-8f);
            ma[k] = m;
            msum += m;
        }
        const float inv = 1.0f / (msum + 1e-8f);
        float acc = 0.0f;
#pragma unroll
        for (int k = 0; k < N_BINS; ++k) {
            float pk = ma[k] * inv;
            acc = fmaf(pk, logf(pk + 1e-8f), acc);
        }
        const float logk = 2.89037175789124f;    // log(18)
        out[(bc * N_PHA + p) * N_AMP + tid] = (logk + acc) / logk;
    }
}

extern "C" void kernel_launch(void* const* d_in, const int* in_sizes, int n_in,
                              void* d_out, int out_size, void* d_ws, size_t ws_size,
                              hipStream_t stream) {
    const float* x    = (const float*)d_in[0];   // (4,16,4096) f32
    const float* filt = (const float*)d_in[1];   // (20,513) f32
    float* out = (float*)d_out;                  // (4,16,10,10) f32

    float* pha = (float*)d_ws;                               // BC*10*T fp32
    unsigned short* amp_bf = (unsigned short*)(pha + BC * N_PHA * T_LEN);

    conv_hilbert_kernel<<<BC * N_BANDS, 256, 0, stream>>>(x, filt, pha, amp_bf);
    bin_mi_mfma<<<BC * N_PHA, 256, 0, stream>>>(pha, amp_bf, out);
}

// Round 3
// 196.052 us; speedup vs baseline: 2.0050x; 1.5545x over previous
//
#include <hip/hip_runtime.h>
#include <math.h>

// Problem constants (match reference)
#define T_LEN 4096
#define FIR_L 513
#define N_PHA 10
#define N_AMP 10
#define N_BANDS 20
#define N_BINS 18
#define BC 64            // B*C = 4*16

typedef __attribute__((ext_vector_type(8))) short short8;
typedef __attribute__((ext_vector_type(4))) float f32x4;

// Skewed LDS index: breaks every power-of-2 lane-stride bank pattern
// (stride 32k words -> 33k -> hits all 32 banks).
#define SKI(i) ((i) + ((i) >> 5))

// float -> bf16 round-to-nearest-even
static __device__ __forceinline__ unsigned short f2bf(float x) {
    unsigned u = __float_as_uint(x);
    unsigned r = u + 0x7FFFu + ((u >> 16) & 1u);
    return (unsigned short)(r >> 16);
}

// ---------------------------------------------------------------------------
// Kernel 1: per (bc, band): FIR bandpass (time domain, 'same' zero-pad) then
// FFT-based Hilbert analytic signal (DIF fwd -> mask -> DIT inv, all in LDS,
// ALL arrays skew-indexed), emit phase fp32 / amplitude bf16.
// ---------------------------------------------------------------------------
__global__ __launch_bounds__(256) void conv_hilbert_kernel(
    const float* __restrict__ x,          // (BC, T)
    const float* __restrict__ filt,       // (20, 513)
    float* __restrict__ pha,              // (BC, 10, T) fp32
    unsigned short* __restrict__ amp_bf)  // (BC, 10, T) bf16 bits
{
    // smem regions (skewed extents):
    //   re : [0, 4224)        SKI(4095)=4222
    //   im : [4224, 8448)
    //   twc: [8448, 10560)    SKI(2047)=2110
    //   tws: [10560, 12672)
    //   xsp (conv phase, aliases re+im): SKI(4607)=4750 < 8448
    __shared__ float smem[12672];
    __shared__ float fs[FIR_L + 3];   // pad for float4 reads

    float* xsp = smem;
    float* re  = smem;
    float* im  = smem + 4224;
    float* twc = smem + 8448;
    float* tws = smem + 10560;

    const int tid  = threadIdx.x;
    const int bc   = blockIdx.x / N_BANDS;
    const int band = blockIdx.x % N_BANDS;

    for (int m = tid; m < 2048; m += 256) {
        float ang = (float)m * (6.283185307179586f / 4096.0f);
        float s, c;
        sincosf(ang, &s, &c);
        twc[SKI(m)] = c;
        tws[SKI(m)] = s;
    }

    // Load padded input row (skewed): xsp[SKI(i)] = x[bc][i-256]
    const float* xrow = x + bc * T_LEN;
    for (int i = tid; i < 4608; i += 256) {
        int src = i - 256;
        xsp[SKI(i)] = (src >= 0 && src < T_LEN) ? xrow[src] : 0.0f;
    }
    for (int i = tid; i < FIR_L; i += 256) fs[i] = filt[band * FIR_L + i];
    if (tid < 3) fs[FIR_L + tid] = 0.0f;
    __syncthreads();

    // ---- Direct conv, rolling 16-register window, skewed LDS reads
    const int t0 = tid * 16;
    float acc[16];
    float v[16];
#pragma unroll
    for (int j = 0; j < 16; ++j) acc[j] = 0.0f;
#pragma unroll
    for (int j = 0; j < 16; ++j) v[j] = xsp[SKI(t0 + j)];

    for (int lb = 0; lb < 512; lb += 16) {
#pragma unroll
        for (int u4 = 0; u4 < 4; ++u4) {
            const float4 fq = *(const float4*)&fs[lb + u4 * 4];
#pragma unroll
            for (int s = 0; s < 4; ++s) {
                const int u = u4 * 4 + s;
                const int l = lb + u;
                const float f = (s == 0) ? fq.x : (s == 1) ? fq.y : (s == 2) ? fq.z : fq.w;
#pragma unroll
                for (int j = 0; j < 16; ++j)
                    acc[j] = fmaf(f, v[(u + j) & 15], acc[j]);
                v[u] = xsp[SKI(t0 + l + 16)];
            }
        }
    }
    {   // last tap l = 512; slot (512+j)&15 == j
        const float f = fs[512];
#pragma unroll
        for (int j = 0; j < 16; ++j)
            acc[j] = fmaf(f, v[j], acc[j]);
    }
    __syncthreads();   // all conv reads of xsp done before aliasing as re/im

#pragma unroll
    for (int j = 0; j < 16; ++j) {
        re[SKI(t0 + j)] = acc[j];
        im[SKI(t0 + j)] = 0.0f;
    }
    __syncthreads();

    // ---- Forward FFT, DIF: natural in -> bit-reversed out
    for (int st = 11; st >= 0; --st) {
        const int h = 1 << st;
#pragma unroll 1
        for (int u = tid; u < 2048; u += 256) {
            const int k  = u & (h - 1);
            const int g  = u >> st;
            const int i  = (g << (st + 1)) + k;
            const int jj = i + h;
            const int m  = k << (11 - st);
            const int si = SKI(i), sj = SKI(jj), sm = SKI(m);
            const float c = twc[sm], s = tws[sm];   // w = c - i*s
            float ar = re[si], ai = im[si], br = re[sj], bi = im[sj];
            re[si] = ar + br;
            im[si] = ai + bi;
            float tr = ar - br, ti = ai - bi;
            re[sj] = fmaf(tr, c,  ti * s);
            im[sj] = fmaf(ti, c, -tr * s);
        }
        __syncthreads();
    }

    // ---- Hilbert mask (bit-reversed order; freq = brev12(i))
    for (int i = tid; i < 4096; i += 256) {
        const int k = (int)(__brev((unsigned)i) >> 20);
        float mfac = (k == 0 || k == 2048) ? 1.0f : (k < 2048 ? 2.0f : 0.0f);
        const int si = SKI(i);
        re[si] *= mfac;
        im[si] *= mfac;
    }
    __syncthreads();

    // ---- Inverse FFT, DIT: bit-reversed in -> natural out
    for (int st = 0; st <= 11; ++st) {
        const int h = 1 << st;
#pragma unroll 1
        for (int u = tid; u < 2048; u += 256) {
            const int k  = u & (h - 1);
            const int g  = u >> st;
            const int i  = (g << (st + 1)) + k;
            const int jj = i + h;
            const int m  = k << (11 - st);
            const int si = SKI(i), sj = SKI(jj), sm = SKI(m);
            const float c = twc[sm], s = tws[sm];   // w = c + i*s
            float br = re[sj], bi = im[sj];
            float tr = fmaf(br, c, -bi * s);
            float ti = fmaf(br, s,  bi * c);
            float ar = re[si], ai = im[si];
            re[si] = ar + tr;
            im[si] = ai + ti;
            re[sj] = ar - tr;
            im[sj] = ai - ti;
        }
        __syncthreads();
    }

    // ---- Emit phase (fp32) or amplitude (bf16)
    const float inv_n = 1.0f / 4096.0f;
    if (band < N_PHA) {
        float* dst = pha + (bc * N_PHA + band) * T_LEN;
        for (int i = tid; i < 4096; i += 256) {
            const int si = SKI(i);
            dst[i] = atan2f(im[si], re[si]);     // scale cancels in atan2
        }
    } else {
        unsigned short* dst = amp_bf + (bc * N_AMP + (band - N_PHA)) * T_LEN;
        for (int i = tid; i < 4096; i += 256) {
            const int si = SKI(i);
            dst[i] = f2bf(sqrtf(re[si] * re[si] + im[si] * im[si]) * inv_n);
        }
    }
}

// ---------------------------------------------------------------------------
// Kernel 2: per (bc, pha-band): 3-bin soft phase binning + einsum via MFMA.
// TEMP=0.01 => softmax is 3-hot: non-neighbor bins < 2e-11 relative (below
// bf16 resolution). w_j = 1/s, w_{j +/- 1} = exp(-D^2/T -/+ 2dD/T)/s.
// GEMM: amp_sum[a][k] = sum_t A[a][t]*w[t][k], A row 10 = ones -> cnt.
// ---------------------------------------------------------------------------
__global__ __launch_bounds__(256) void bin_mi_mfma(
    const float* __restrict__ pha,             // (BC, 10, T) fp32
    const unsigned short* __restrict__ amp_bf, // (BC, 10, T) bf16 bits
    float* __restrict__ out)                   // (BC, 10, 10)
{
    const int tid  = threadIdx.x;
    const int lane = tid & 63;
    const int wv   = tid >> 6;        // 0..3
    const int bc   = blockIdx.x / N_PHA;
    const int p    = blockIdx.x % N_PHA;

    // per-wave w buffer: 18 rows x 68 words (136 bf16 = 128 samples + pad)
    __shared__ unsigned int wbufW[4][18 * 68];
    __shared__ float psum[4][11][N_BINS];
    __shared__ float asum[11][N_BINS];

    const float* phrow = pha + (bc * N_PHA + p) * T_LEN;
    const unsigned short* arow = amp_bf + bc * N_AMP * T_LEN;

    const float PI_F  = 3.14159274101257324f;
    const float INVD  = 2.8647889756541160f;   // 9/pi = 1/(2pi/18)
    const float DELTA = 0.34906585039886590f;  // 2pi/18
    const float C1    = 12.184696791468343f;   // DELTA^2 / 0.01
    const float C2    = 69.813170079773180f;   // 2*DELTA / 0.01

    const int m_ = lane & 15;         // A row
    const int q_ = lane >> 4;         // 0..3
    const int n_ = lane & 15;         // B col (bin)

    short8 zero8;
#pragma unroll
    for (int j = 0; j < 8; ++j) zero8[j] = 0;
    short8 ones8;
#pragma unroll
    for (int j = 0; j < 8; ++j) ones8[j] = (short)0x3F80;   // bf16 1.0

    f32x4 acc0 = {0.f, 0.f, 0.f, 0.f};   // bins 0..15
    f32x4 acc1 = {0.f, 0.f, 0.f, 0.f};   // bins 16..17 (cols 0,1)

    const int base_t = wv * 1024;
    unsigned short* wh = (unsigned short*)&wbufW[wv][0];

    for (int chunk = 0; chunk < 8; ++chunk) {
        const int cb = base_t + chunk * 128;
        const int ts = cb + lane * 2;
        const float ph0 = phrow[ts];
        const float ph1 = phrow[ts + 1];

        // zero this lane's column in all 18 rows
#pragma unroll
        for (int k = 0; k < N_BINS; ++k)
            wbufW[wv][k * 68 + lane] = 0u;

        // 3-bin softmax, two samples (halves of the packed word)
#pragma unroll
        for (int h = 0; h < 2; ++h) {
            const float ph = h ? ph1 : ph0;
            float u  = (ph + PI_F) * INVD;       // in [0, 18]
            float jf = floorf(u);
            float d  = (u - jf - 0.5f) * DELTA;  // dist to center, [-D/2, D/2]
            int j0 = (int)jf;
            if (j0 >= N_BINS) j0 -= N_BINS;      // ph == +pi wraps to bin 0
            const int jm = (j0 == 0) ? N_BINS - 1 : j0 - 1;
            const int jp = (j0 == N_BINS - 1) ? 0 : j0 + 1;
            const float em = expf(-C1 - C2 * d);
            const float ep = expf(-C1 + C2 * d);
            const float inv = 1.0f / (1.0f + em + ep);
            wh[(j0 * 68 + lane) * 2 + h] = f2bf(inv);
            wh[(jm * 68 + lane) * 2 + h] = f2bf(em * inv);
            wh[(jp * 68 + lane) * 2 + h] = f2bf(ep * inv);
        }
        __syncthreads();

        // ---- 4 MFMA K-steps (K=32 each) over this 128-sample chunk
#pragma unroll
        for (int s = 0; s < 4; ++s) {
            const int tA = cb + s * 32 + q_ * 8;
            short8 afrag;
            if (m_ < N_AMP) {
                afrag = *(const short8*)(arow + m_ * T_LEN + tA);
            } else if (m_ == N_AMP) {
                afrag = ones8;
            } else {
                afrag = zero8;
            }
            const int woff = s * 16 + q_ * 4;
            short8 bfrag0 = *(const short8*)&wbufW[wv][n_ * 68 + woff];
            short8 bfrag1 = (n_ < 2)
                ? *(const short8*)&wbufW[wv][(16 + n_) * 68 + woff]
                : zero8;
            acc0 = __builtin_amdgcn_mfma_f32_16x16x32_bf16(afrag, bfrag0, acc0, 0, 0, 0);
            acc1 = __builtin_amdgcn_mfma_f32_16x16x32_bf16(afrag, bfrag1, acc1, 0, 0, 0);
        }
        __syncthreads();   // protect wbufW before next chunk's writes
    }

    // ---- write per-wave C tiles (C/D: col=lane&15, row=(lane>>4)*4+reg)
#pragma unroll
    for (int r = 0; r < 4; ++r) {
        const int m = q_ * 4 + r;
        if (m < 11) {
            psum[wv][m][n_] = acc0[r];
            if (n_ < 2) psum[wv][m][16 + n_] = acc1[r];
        }
    }
    __syncthreads();

    // ---- reduce 4 waves
    if (tid < 11 * N_BINS) {
        const int m = tid / N_BINS;
        const int k = tid % N_BINS;
        asum[m][k] = psum[0][m][k] + psum[1][m][k] + psum[2][m][k] + psum[3][m][k];
    }
    __syncthreads();

    // ---- MI per amp band
    if (tid < N_AMP) {
        float ma[N_BINS];
        float msum = 0.0f;
#pragma unroll
        for (int k = 0; k < N_BINS; ++k) {
            float m = asum[tid][k] / (asum[10][k] + 1e-8f);
            ma[k] = m;
            msum += m;
        }
        const float inv = 1.0f / (msum + 1e-8f);
        float acc = 0.0f;
#pragma unroll
        for (int k = 0; k < N_BINS; ++k) {
            float pk = ma[k] * inv;
            acc = fmaf(pk, logf(pk + 1e-8f), acc);
        }
        const float logk = 2.89037175789124f;    // log(18)
        out[(bc * N_PHA + p) * N_AMP + tid] = (logk + acc) / logk;
    }
}

extern "C" void kernel_launch(void* const* d_in, const int* in_sizes, int n_in,
                              void* d_out, int out_size, void* d_ws, size_t ws_size,
                              hipStream_t stream) {
    const float* x    = (const float*)d_in[0];   // (4,16,4096) f32
    const float* filt = (const float*)d_in[1];   // (20,513) f32
    float* out = (float*)d_out;                  // (4,16,10,10) f32

    float* pha = (float*)d_ws;                               // BC*10*T fp32
    unsigned short* amp_bf = (unsigned short*)(pha + BC * N_PHA * T_LEN);

    conv_hilbert_kernel<<<BC * N_BANDS, 256, 0, stream>>>(x, filt, pha, amp_bf);
    bin_mi_mfma<<<BC * N_PHA, 256, 0, stream>>>(pha, amp_bf, out);
}

// Round 5
// 178.156 us; speedup vs baseline: 2.2064x; 1.1004x over previous
//
#include <hip/hip_runtime.h>
#include <math.h>

// Problem constants (match reference)
#define T_LEN 4096
#define FIR_L 513
#define N_PHA 10
#define N_AMP 10
#define N_BANDS 20
#define N_BINS 18
#define BC 64            // B*C = 4*16

typedef __attribute__((ext_vector_type(8))) short short8;
typedef __attribute__((ext_vector_type(4))) float f32x4;

// Skewed b32 index (conv staging): breaks power-of-2 lane strides.
#define SKI(i) ((i) + ((i) >> 5))
// Interleaved-complex skewed addresses (float index of re; im at +1).
// Even skew keeps 8-byte alignment for b64 LDS ops.
// Extents: ZA(4095)+2 = 8702 -> z region 8704 floats.
//          TA(1023)+2 = 2174 -> tw region 2176 floats.
#define ZA(i) (((i) << 1) + ((((i) >> 4)) << 1))
#define TA(m) (((m) << 1) + ((((m) >> 4)) << 1))

// float -> bf16 round-to-nearest-even
static __device__ __forceinline__ unsigned short f2bf(float x) {
    unsigned u = __float_as_uint(x);
    unsigned r = u + 0x7FFFu + ((u >> 16) & 1u);
    return (unsigned short)(r >> 16);
}

// storage index -> frequency after radix-4 DIF (base-4 digit reversal)
static __device__ __forceinline__ int digitrev12(int p) {
    unsigned rr = __brev((unsigned)p) >> 20;               // 12-bit bit reversal
    rr = ((rr & 0x555u) << 1) | ((rr & 0xAAAu) >> 1);      // swap bit pairs
    return (int)rr;
}

// ---------------------------------------------------------------------------
// Kernel 1: per (bc, band): FIR bandpass (time-domain, 'same' zero-pad) then
// radix-4 FFT Hilbert analytic signal (DIF fwd w/ fused mask -> DIT inv),
// interleaved complex in LDS; emit phase fp32 / amplitude bf16.
// ---------------------------------------------------------------------------
__global__ __launch_bounds__(256) void conv_hilbert_kernel(
    const float* __restrict__ x,          // (BC, T)
    const float* __restrict__ filt,       // (20, 513)
    float* __restrict__ pha,              // (BC, 10, T) fp32
    unsigned short* __restrict__ amp_bf)  // (BC, 10, T) bf16 bits
{
    // smem: z (interleaved complex, skewed) [0, 8704); tw [8704, 10880)
    // conv staging xsp aliases z region (SKI extent 4750 < 8704).
    // Total: (10880 + 516) * 4 B ~= 45.6 KB -> 3 blocks/CU.
    __shared__ float smem[10880];
    __shared__ float fs[FIR_L + 3];

    float* xsp = smem;
    float* z   = smem;
    float* tw  = smem + 8704;

    const int tid  = threadIdx.x;
    const int bc   = blockIdx.x / N_BANDS;
    const int band = blockIdx.x % N_BANDS;

    // Twiddle table: tw[m] = (cos, sin) of 2*pi*m/4096, m in [0,1024).
    // W^{2m}, W^{3m} are derived in-register (double-angle / angle-sum).
    for (int m = tid; m < 1024; m += 256) {
        float ang = (float)m * (6.283185307179586f / 4096.0f);
        float s, c;
        sincosf(ang, &s, &c);
        tw[TA(m)]     = c;
        tw[TA(m) + 1] = s;
    }

    // Load padded input row (skewed): xsp[SKI(i)] = x[bc][i-256]
    const float* xrow = x + bc * T_LEN;
    for (int i = tid; i < 4608; i += 256) {
        int src = i - 256;
        xsp[SKI(i)] = (src >= 0 && src < T_LEN) ? xrow[src] : 0.0f;
    }
    for (int i = tid; i < FIR_L; i += 256) fs[i] = filt[band * FIR_L + i];
    if (tid < 3) fs[FIR_L + tid] = 0.0f;
    __syncthreads();

    // ---- Direct conv, rolling 16-register window, skewed LDS reads
    const int t0 = tid * 16;
    float acc[16];
    float v[16];
#pragma unroll
    for (int j = 0; j < 16; ++j) acc[j] = 0.0f;
#pragma unroll
    for (int j = 0; j < 16; ++j) v[j] = xsp[SKI(t0 + j)];

    for (int lb = 0; lb < 512; lb += 16) {
#pragma unroll
        for (int u4 = 0; u4 < 4; ++u4) {
            const float4 fq = *(const float4*)&fs[lb + u4 * 4];
#pragma unroll
            for (int s = 0; s < 4; ++s) {
                const int u = u4 * 4 + s;
                const int l = lb + u;
                const float f = (s == 0) ? fq.x : (s == 1) ? fq.y : (s == 2) ? fq.z : fq.w;
#pragma unroll
                for (int j = 0; j < 16; ++j)
                    acc[j] = fmaf(f, v[(u + j) & 15], acc[j]);
                v[u] = xsp[SKI(t0 + l + 16)];
            }
        }
    }
    {   // last tap l = 512
        const float f = fs[512];
#pragma unroll
        for (int j = 0; j < 16; ++j)
            acc[j] = fmaf(f, v[j], acc[j]);
    }
    __syncthreads();   // conv reads of xsp done before aliasing as z

#pragma unroll
    for (int j = 0; j < 16; ++j) {
        float2* zp = (float2*)&z[ZA(t0 + j)];
        *zp = make_float2(acc[j], 0.0f);
    }
    __syncthreads();

    // ---- Forward radix-4 DIF (natural -> base-4 digit-reversed), fused mask
    for (int s = 0; s < 6; ++s) {
        const int hl = 10 - 2 * s;
        const int h  = 1 << hl;
#pragma unroll
        for (int r = 0; r < 4; ++r) {
            const int u  = tid + (r << 8);
            const int k  = u & (h - 1);
            const int g  = u >> hl;
            const int i0 = (g << (hl + 2)) + k;
            const int m1 = k << (2 * s);                 // < 1024
            const float2 w1 = *(const float2*)&tw[TA(m1)];
            const float c1 = w1.x, s1 = w1.y;
            const float s2 = 2.0f * s1 * c1;             // double angle
            const float c2 = fmaf(-2.0f * s1, s1, 1.0f);
            const float c3 = c1 * c2 - s1 * s2;          // angle sum
            const float s3 = s1 * c2 + c1 * s2;

            float2 a = *(const float2*)&z[ZA(i0)];
            float2 b = *(const float2*)&z[ZA(i0 + h)];
            float2 c = *(const float2*)&z[ZA(i0 + 2 * h)];
            float2 d = *(const float2*)&z[ZA(i0 + 3 * h)];

            const float t0r = a.x + c.x, t0i = a.y + c.y;
            const float t1r = a.x - c.x, t1i = a.y - c.y;
            const float t2r = b.x + d.x, t2i = b.y + d.y;
            const float t3r = b.x - d.x, t3i = b.y - d.y;

            float y0r = t0r + t2r,  y0i = t0i + t2i;
            const float u1r = t1r + t3i, u1i = t1i - t3r;   // t1 - i*t3
            const float u2r = t0r - t2r, u2i = t0i - t2i;
            const float u3r = t1r - t3i, u3i = t1i + t3r;   // t1 + i*t3
            // multiply by e^{-i theta}: (xr*c + xi*s, xi*c - xr*s)
            float y1r = u1r * c1 + u1i * s1, y1i = u1i * c1 - u1r * s1;
            float y2r = u2r * c2 + u2i * s2, y2i = u2i * c2 - u2r * s2;
            float y3r = u3r * c3 + u3i * s3, y3i = u3i * c3 - u3r * s3;

            if (s == 5) {   // fused Hilbert mask on digit-reversed storage
#pragma unroll
                for (int q = 0; q < 4; ++q) {
                    const int f = digitrev12(i0 + q);
                    const float mf = (f == 0 || f == 2048) ? 1.0f
                                    : (f < 2048 ? 2.0f : 0.0f);
                    if (q == 0) { y0r *= mf; y0i *= mf; }
                    else if (q == 1) { y1r *= mf; y1i *= mf; }
                    else if (q == 2) { y2r *= mf; y2i *= mf; }
                    else { y3r *= mf; y3i *= mf; }
                }
            }

            *(float2*)&z[ZA(i0)]         = make_float2(y0r, y0i);
            *(float2*)&z[ZA(i0 + h)]     = make_float2(y1r, y1i);
            *(float2*)&z[ZA(i0 + 2 * h)] = make_float2(y2r, y2i);
            *(float2*)&z[ZA(i0 + 3 * h)] = make_float2(y3r, y3i);
        }
        __syncthreads();
    }

    // ---- Inverse radix-4 DIT (digit-reversed -> natural), e^{+i theta}
    for (int s = 0; s < 6; ++s) {
        const int hl = 2 * s;
        const int L  = 1 << hl;
#pragma unroll
        for (int r = 0; r < 4; ++r) {
            const int u  = tid + (r << 8);
            const int k  = u & (L - 1);
            const int g  = u >> hl;
            const int i0 = (g << (hl + 2)) + k;
            const int m1 = k << (10 - hl);               // < 1024
            const float2 w1 = *(const float2*)&tw[TA(m1)];
            const float c1 = w1.x, s1 = w1.y;
            const float s2 = 2.0f * s1 * c1;
            const float c2 = fmaf(-2.0f * s1, s1, 1.0f);
            const float c3 = c1 * c2 - s1 * s2;
            const float s3 = s1 * c2 + c1 * s2;

            float2 a = *(const float2*)&z[ZA(i0)];
            float2 b = *(const float2*)&z[ZA(i0 + L)];
            float2 c = *(const float2*)&z[ZA(i0 + 2 * L)];
            float2 d = *(const float2*)&z[ZA(i0 + 3 * L)];

            // tb = b*(c1 + i s1), tc = c*(c2 + i s2), td = d*(c3 + i s3)
            const float tbr = b.x * c1 - b.y * s1, tbi = b.y * c1 + b.x * s1;
            const float tcr = c.x * c2 - c.y * s2, tci = c.y * c2 + c.x * s2;
            const float tdr = d.x * c3 - d.y * s3, tdi = d.y * c3 + d.x * s3;

            const float y0r = a.x + tbr + tcr + tdr;
            const float y0i = a.y + tbi + tci + tdi;
            const float y1r = a.x - tbi - tcr + tdi;   // a + i*tb - tc - i*td
            const float y1i = a.y + tbr - tci - tdr;
            const float y2r = a.x - tbr + tcr - tdr;
            const float y2i = a.y - tbi + tci - tdi;
            const float y3r = a.x + tbi - tcr - tdi;   // a - i*tb - tc + i*td
            const float y3i = a.y - tbr - tci + tdr;

            *(float2*)&z[ZA(i0)]         = make_float2(y0r, y0i);
            *(float2*)&z[ZA(i0 + L)]     = make_float2(y1r, y1i);
            *(float2*)&z[ZA(i0 + 2 * L)] = make_float2(y2r, y2i);
            *(float2*)&z[ZA(i0 + 3 * L)] = make_float2(y3r, y3i);
        }
        __syncthreads();
    }

    // ---- Emit phase (fp32) or amplitude (bf16)
    const float inv_n = 1.0f / 4096.0f;
    if (band < N_PHA) {
        float* dst = pha + (bc * N_PHA + band) * T_LEN;
        for (int i = tid; i < 4096; i += 256) {
            const float2 zz = *(const float2*)&z[ZA(i)];
            dst[i] = atan2f(zz.y, zz.x);         // scale cancels in atan2
        }
    } else {
        unsigned short* dst = amp_bf + (bc * N_AMP + (band - N_PHA)) * T_LEN;
        for (int i = tid; i < 4096; i += 256) {
            const float2 zz = *(const float2*)&z[ZA(i)];
            dst[i] = f2bf(sqrtf(zz.x * zz.x + zz.y * zz.y) * inv_n);
        }
    }
}

// ---------------------------------------------------------------------------
// Kernel 2: per (bc, pha-band): 3-hot soft phase binning + einsum via MFMA.
// Waves are fully independent across K-quarters (private wbuf regions) ->
// no per-chunk __syncthreads; DS ops within a wave complete in order.
// ---------------------------------------------------------------------------
__global__ __launch_bounds__(256) void bin_mi_mfma(
    const float* __restrict__ pha,             // (BC, 10, T) fp32
    const unsigned short* __restrict__ amp_bf, // (BC, 10, T) bf16 bits
    float* __restrict__ out)                   // (BC, 10, 10)
{
    const int tid  = threadIdx.x;
    const int lane = tid & 63;
    const int wv   = tid >> 6;        // 0..3
    const int bc   = blockIdx.x / N_PHA;
    const int p    = blockIdx.x % N_PHA;

    __shared__ unsigned int wbufW[4][18 * 68];  // per-wave, 128 samples + pad
    __shared__ float psum[4][11][N_BINS];
    __shared__ float asum[11][N_BINS];

    const float* phrow = pha + (bc * N_PHA + p) * T_LEN;
    const unsigned short* arow = amp_bf + bc * N_AMP * T_LEN;

    const float PI_F  = 3.14159274101257324f;
    const float INVD  = 2.8647889756541160f;   // 9/pi
    const float DELTA = 0.34906585039886590f;  // 2pi/18
    const float C1    = 12.184696791468343f;   // DELTA^2 / 0.01
    const float C2    = 69.813170079773180f;   // 2*DELTA / 0.01

    const int m_ = lane & 15;
    const int q_ = lane >> 4;
    const int n_ = lane & 15;

    short8 zero8;
#pragma unroll
    for (int j = 0; j < 8; ++j) zero8[j] = 0;
    short8 ones8;
#pragma unroll
    for (int j = 0; j < 8; ++j) ones8[j] = (short)0x3F80;   // bf16 1.0

    f32x4 acc0 = {0.f, 0.f, 0.f, 0.f};   // bins 0..15
    f32x4 acc1 = {0.f, 0.f, 0.f, 0.f};   // bins 16..17

    const int base_t = wv * 1024;
    unsigned short* wh = (unsigned short*)&wbufW[wv][0];

    for (int chunk = 0; chunk < 8; ++chunk) {
        const int cb = base_t + chunk * 128;
        const float2 pp = *(const float2*)&phrow[cb + lane * 2];

        // zero this lane's column in all 18 rows
#pragma unroll
        for (int k = 0; k < N_BINS; ++k)
            wbufW[wv][k * 68 + lane] = 0u;

        // 3-hot softmax, two samples
#pragma unroll
        for (int h = 0; h < 2; ++h) {
            const float ph = h ? pp.y : pp.x;
            float u  = (ph + PI_F) * INVD;       // in [0, 18]
            float jf = floorf(u);
            float d  = (u - jf - 0.5f) * DELTA;
            int j0 = (int)jf;
            if (j0 >= N_BINS) j0 -= N_BINS;      // ph == +pi wraps
            const int jm = (j0 == 0) ? N_BINS - 1 : j0 - 1;
            const int jp = (j0 == N_BINS - 1) ? 0 : j0 + 1;
            const float em = expf(-C1 - C2 * d);
            const float ep = expf(-C1 + C2 * d);
            const float inv = 1.0f / (1.0f + em + ep);
            wh[(j0 * 68 + lane) * 2 + h] = f2bf(inv);
            wh[(jm * 68 + lane) * 2 + h] = f2bf(em * inv);
            wh[(jp * 68 + lane) * 2 + h] = f2bf(ep * inv);
        }
        __builtin_amdgcn_wave_barrier();   // pin: w stores before frag reads

        // ---- 4 MFMA K-steps (K=32 each)
#pragma unroll
        for (int s = 0; s < 4; ++s) {
            const int tA = cb + s * 32 + q_ * 8;
            short8 afrag;
            if (m_ < N_AMP) {
                afrag = *(const short8*)(arow + m_ * T_LEN + tA);
            } else if (m_ == N_AMP) {
                afrag = ones8;
            } else {
                afrag = zero8;
            }
            const int woff = s * 16 + q_ * 4;
            short8 bfrag0 = *(const short8*)&wbufW[wv][n_ * 68 + woff];
            short8 bfrag1 = (n_ < 2)
                ? *(const short8*)&wbufW[wv][(16 + n_) * 68 + woff]
                : zero8;
            acc0 = __builtin_amdgcn_mfma_f32_16x16x32_bf16(afrag, bfrag0, acc0, 0, 0, 0);
            acc1 = __builtin_amdgcn_mfma_f32_16x16x32_bf16(afrag, bfrag1, acc1, 0, 0, 0);
        }
        __builtin_amdgcn_wave_barrier();   // pin: frag reads before next zeroing
    }

    // ---- per-wave C tiles (C/D: col=lane&15, row=(lane>>4)*4+reg)
#pragma unroll
    for (int r = 0; r < 4; ++r) {
        const int m = q_ * 4 + r;
        if (m < 11) {
            psum[wv][m][n_] = acc0[r];
            if (n_ < 2) psum[wv][m][16 + n_] = acc1[r];
        }
    }
    __syncthreads();

    if (tid < 11 * N_BINS) {
        const int m = tid / N_BINS;
        const int k = tid % N_BINS;
        asum[m][k] = psum[0][m][k] + psum[1][m][k] + psum[2][m][k] + psum[3][m][k];
    }
    __syncthreads();

    if (tid < N_AMP) {
        float ma[N_BINS];
        float msum = 0.0f;
#pragma unroll
        for (int k = 0; k < N_BINS; ++k) {
            float m = asum[tid][k] / (asum[10][k] + 1e-8f);
            ma[k] = m;
            msum += m;
        }
        const float inv = 1.0f / (msum + 1e-8f);
        float acc = 0.0f;
#pragma unroll
        for (int k = 0; k < N_BINS; ++k) {
            float pk = ma[k] * inv;
            acc = fmaf(pk, logf(pk + 1e-8f), acc);
        }
        const float logk = 2.89037175789124f;    // log(18)
        out[(bc * N_PHA + p) * N_AMP + tid] = (logk + acc) / logk;
    }
}

extern "C" void kernel_launch(void* const* d_in, const int* in_sizes, int n_in,
                              void* d_out, int out_size, void* d_ws, size_t ws_size,
                              hipStream_t stream) {
    const float* x    = (const float*)d_in[0];   // (4,16,4096) f32
    const float* filt = (const float*)d_in[1];   // (20,513) f32
    float* out = (float*)d_out;                  // (4,16,10,10) f32

    float* pha = (float*)d_ws;                               // BC*10*T fp32
    unsigned short* amp_bf = (unsigned short*)(pha + BC * N_PHA * T_LEN);

    conv_hilbert_kernel<<<BC * N_BANDS, 256, 0, stream>>>(x, filt, pha, amp_bf);
    bin_mi_mfma<<<BC * N_PHA, 256, 0, stream>>>(pha, amp_bf, out);
}

// Round 6
// 145.243 us; speedup vs baseline: 2.7064x; 1.2266x over previous
//
#include <hip/hip_runtime.h>
#include <math.h>

// Problem constants (match reference)
#define T_LEN 4096
#define FIR_L 513
#define N_PHA 10
#define N_AMP 10
#define N_BANDS 20
#define N_BINS 18
#define BC 64            // B*C = 4*16

typedef __attribute__((ext_vector_type(8))) short short8;
typedef __attribute__((ext_vector_type(4))) float f32x4;

// Interleaved-complex skewed addresses (float index of re; im at +1).
// Even skew keeps 8-byte alignment for b64 LDS ops.
// Extents: ZA(4095)+2 = 8702 -> z region 8704 floats.
//          TA(1023)+2 = 2174 -> tw region 2176 floats.
#define ZA(i) (((i) << 1) + ((((i) >> 4)) << 1))
#define TA(m) (((m) << 1) + ((((m) >> 4)) << 1))

// float -> bf16 round-to-nearest-even
static __device__ __forceinline__ unsigned short f2bf(float x) {
    unsigned u = __float_as_uint(x);
    unsigned r = u + 0x7FFFu + ((u >> 16) & 1u);
    return (unsigned short)(r >> 16);
}

// storage index -> frequency after radix-4 DIF (base-4 digit reversal)
static __device__ __forceinline__ int digitrev12(int p) {
    unsigned rr = __brev((unsigned)p) >> 20;               // 12-bit bit reversal
    rr = ((rr & 0x555u) << 1) | ((rr & 0xAAAu) >> 1);      // swap bit pairs
    return (int)rr;
}

// Forward radix-4 DIF, natural -> base-4 digit-reversed. tw[m]=(c,s) m<1024.
static __device__ __forceinline__ void fft_fwd6(float* z, const float* tw, int tid) {
    for (int s = 0; s < 6; ++s) {
        const int hl = 10 - 2 * s;
        const int h  = 1 << hl;
#pragma unroll
        for (int r = 0; r < 4; ++r) {
            const int u  = tid + (r << 8);
            const int k  = u & (h - 1);
            const int g  = u >> hl;
            const int i0 = (g << (hl + 2)) + k;
            const int m1 = k << (2 * s);                 // < 1024
            const float2 w1 = *(const float2*)&tw[TA(m1)];
            const float c1 = w1.x, s1 = w1.y;
            const float s2 = 2.0f * s1 * c1;             // double angle
            const float c2 = fmaf(-2.0f * s1, s1, 1.0f);
            const float c3 = c1 * c2 - s1 * s2;          // angle sum
            const float s3 = s1 * c2 + c1 * s2;

            float2 a = *(const float2*)&z[ZA(i0)];
            float2 b = *(const float2*)&z[ZA(i0 + h)];
            float2 c = *(const float2*)&z[ZA(i0 + 2 * h)];
            float2 d = *(const float2*)&z[ZA(i0 + 3 * h)];

            const float t0r = a.x + c.x, t0i = a.y + c.y;
            const float t1r = a.x - c.x, t1i = a.y - c.y;
            const float t2r = b.x + d.x, t2i = b.y + d.y;
            const float t3r = b.x - d.x, t3i = b.y - d.y;

            const float y0r = t0r + t2r,  y0i = t0i + t2i;
            const float u1r = t1r + t3i, u1i = t1i - t3r;   // t1 - i*t3
            const float u2r = t0r - t2r, u2i = t0i - t2i;
            const float u3r = t1r - t3i, u3i = t1i + t3r;   // t1 + i*t3
            // multiply by e^{-i theta}
            const float y1r = u1r * c1 + u1i * s1, y1i = u1i * c1 - u1r * s1;
            const float y2r = u2r * c2 + u2i * s2, y2i = u2i * c2 - u2r * s2;
            const float y3r = u3r * c3 + u3i * s3, y3i = u3i * c3 - u3r * s3;

            *(float2*)&z[ZA(i0)]         = make_float2(y0r, y0i);
            *(float2*)&z[ZA(i0 + h)]     = make_float2(y1r, y1i);
            *(float2*)&z[ZA(i0 + 2 * h)] = make_float2(y2r, y2i);
            *(float2*)&z[ZA(i0 + 3 * h)] = make_float2(y3r, y3i);
        }
        __syncthreads();
    }
}

// Inverse radix-4 DIT, base-4 digit-reversed -> natural (unscaled).
static __device__ __forceinline__ void fft_inv6(float* z, const float* tw, int tid) {
    for (int s = 0; s < 6; ++s) {
        const int hl = 2 * s;
        const int L  = 1 << hl;
#pragma unroll
        for (int r = 0; r < 4; ++r) {
            const int u  = tid + (r << 8);
            const int k  = u & (L - 1);
            const int g  = u >> hl;
            const int i0 = (g << (hl + 2)) + k;
            const int m1 = k << (10 - hl);               // < 1024
            const float2 w1 = *(const float2*)&tw[TA(m1)];
            const float c1 = w1.x, s1 = w1.y;
            const float s2 = 2.0f * s1 * c1;
            const float c2 = fmaf(-2.0f * s1, s1, 1.0f);
            const float c3 = c1 * c2 - s1 * s2;
            const float s3 = s1 * c2 + c1 * s2;

            float2 a = *(const float2*)&z[ZA(i0)];
            float2 b = *(const float2*)&z[ZA(i0 + L)];
            float2 c = *(const float2*)&z[ZA(i0 + 2 * L)];
            float2 d = *(const float2*)&z[ZA(i0 + 3 * L)];

            // tb = b*(c1 + i s1), tc = c*(c2 + i s2), td = d*(c3 + i s3)
            const float tbr = b.x * c1 - b.y * s1, tbi = b.y * c1 + b.x * s1;
            const float tcr = c.x * c2 - c.y * s2, tci = c.y * c2 + c.x * s2;
            const float tdr = d.x * c3 - d.y * s3, tdi = d.y * c3 + d.x * s3;

            const float y0r = a.x + tbr + tcr + tdr;
            const float y0i = a.y + tbi + tci + tdi;
            const float y1r = a.x - tbi - tcr + tdi;   // a + i*tb - tc - i*td
            const float y1i = a.y + tbr - tci - tdr;
            const float y2r = a.x - tbr + tcr - tdr;
            const float y2i = a.y - tbi + tci - tdi;
            const float y3r = a.x + tbi - tcr - tdi;   // a - i*tb - tc + i*td
            const float y3i = a.y - tbr - tci + tdr;

            *(float2*)&z[ZA(i0)]         = make_float2(y0r, y0i);
            *(float2*)&z[ZA(i0 + L)]     = make_float2(y1r, y1i);
            *(float2*)&z[ZA(i0 + 2 * L)] = make_float2(y2r, y2i);
            *(float2*)&z[ZA(i0 + 3 * L)] = make_float2(y3r, y3i);
        }
        __syncthreads();
    }
}

// ---------------------------------------------------------------------------
// Precompute: blocks 0..63 -> X[bc] = FFT(x row); blocks 64..83 ->
// Hf[band] = FFT(circularly-placed correlation kernel h[n]=f[256-n]).
// Spectra stored in base-4 digit-reversed index order (consistent everywhere).
// ---------------------------------------------------------------------------
__global__ __launch_bounds__(256) void spectral_pre(
    const float* __restrict__ x,      // (BC, T)
    const float* __restrict__ filt,   // (20, 513)
    float2* __restrict__ Xs,          // (BC, 4096)
    float2* __restrict__ Hs)          // (20, 4096)
{
    __shared__ float smem[10880];
    __shared__ float fb[FIR_L];
    float* z  = smem;
    float* tw = smem + 8704;

    const int tid = threadIdx.x;
    const int b   = blockIdx.x;

    for (int m = tid; m < 1024; m += 256) {
        float ang = (float)m * (6.283185307179586f / 4096.0f);
        float s, c;
        sincosf(ang, &s, &c);
        tw[TA(m)]     = c;
        tw[TA(m) + 1] = s;
    }

    if (b < BC) {
        const float* xrow = x + b * T_LEN;
        for (int i = tid; i < 4096; i += 256)
            *(float2*)&z[ZA(i)] = make_float2(xrow[i], 0.0f);
    } else {
        const int band = b - BC;
        for (int i = tid; i < FIR_L; i += 256) fb[i] = filt[band * FIR_L + i];
        __syncthreads();
        // h[n] = f[256-n] for n in [0,257); h[n] = f[4352-n] for n in [3840,4096)
        for (int i = tid; i < 4096; i += 256) {
            float hv = 0.0f;
            if (i < 257)        hv = fb[256 - i];
            else if (i >= 3840) hv = fb[4352 - i];
            *(float2*)&z[ZA(i)] = make_float2(hv, 0.0f);
        }
    }
    __syncthreads();

    fft_fwd6(z, tw, tid);

    float2* dst = (b < BC) ? (Xs + b * 4096) : (Hs + (b - BC) * 4096);
    for (int i = tid; i < 4096; i += 256)
        dst[i] = *(const float2*)&z[ZA(i)];
}

// ---------------------------------------------------------------------------
// Main: per (bc, band): analytic = IFFT( mask * (X*Hf + FFT(corr)) ), where
// corr fixes circular->linear conv on the 512 boundary samples (257 balanced
// FMAs/thread). Emit phase fp32 / amplitude bf16.
// ---------------------------------------------------------------------------
__global__ __launch_bounds__(256) void spectral_main(
    const float* __restrict__ x,          // (BC, T)
    const float* __restrict__ filt,       // (20, 513)
    const float2* __restrict__ Xs,        // (BC, 4096)
    const float2* __restrict__ Hs,        // (20, 4096)
    float* __restrict__ pha,              // (BC, 10, T) fp32
    unsigned short* __restrict__ amp_bf)  // (BC, 10, T) bf16 bits
{
    __shared__ float smem[10880];   // z [0,8704), tw [8704,10880)
    __shared__ float xe[512];       // x[0..255] | x[3840..4095]
    __shared__ float fb[FIR_L];
    float* z  = smem;
    float* tw = smem + 8704;

    const int tid  = threadIdx.x;
    const int bc   = blockIdx.x / N_BANDS;
    const int band = blockIdx.x % N_BANDS;

    for (int m = tid; m < 1024; m += 256) {
        float ang = (float)m * (6.283185307179586f / 4096.0f);
        float s, c;
        sincosf(ang, &s, &c);
        tw[TA(m)]     = c;
        tw[TA(m) + 1] = s;
    }

    const float* xrow = x + bc * T_LEN;
    for (int i = tid; i < 512; i += 256)
        xe[i] = (i < 256) ? xrow[i] : xrow[3584 + i];   // 3584+i = 3840+(i-256)
    for (int i = tid; i < FIR_L; i += 256) fb[i] = filt[band * FIR_L + i];
    __syncthreads();

    // ---- boundary correction (linear - circular), 257 FMAs/thread
    // front t=tid:      corr[t]      = -sum_{l=0}^{255-t} f[l]*x[3840+t+l]
    // tail  t=3840+tid: corr[t]      = -sum_{j=0}^{tid}   f[512-tid+j]*x[j]
    float cf = 0.0f, ct = 0.0f;
    for (int l = 0; l <= 255 - tid; ++l)
        cf = fmaf(fb[l], xe[256 + tid + l], cf);
    for (int j = 0; j <= tid; ++j)
        ct = fmaf(fb[512 - tid + j], xe[j], ct);

    // stage corr as complex signal (zero middle)
    for (int i = tid; i < 4096; i += 256)
        *(float2*)&z[ZA(i)] = make_float2(0.0f, 0.0f);
    *(float2*)&z[ZA(tid)]        = make_float2(-cf, 0.0f);
    *(float2*)&z[ZA(3840 + tid)] = make_float2(-ct, 0.0f);
    __syncthreads();

    fft_fwd6(z, tw, tid);    // C = FFT(corr), digit-reversed

    // ---- pointwise: P = X*Hf + C, Hilbert mask, back into z
    const float2* Xrow = Xs + bc * 4096;
    const float2* Hrow = Hs + band * 4096;
    for (int i = tid; i < 4096; i += 256) {
        const float2 X = Xrow[i];
        const float2 H = Hrow[i];
        const float2 C = *(const float2*)&z[ZA(i)];
        float pr = X.x * H.x - X.y * H.y + C.x;
        float pi = X.x * H.y + X.y * H.x + C.y;
        const int f = digitrev12(i);
        const float mf = (f == 0 || f == 2048) ? 1.0f : (f < 2048 ? 2.0f : 0.0f);
        *(float2*)&z[ZA(i)] = make_float2(pr * mf, pi * mf);
    }
    __syncthreads();

    fft_inv6(z, tw, tid);    // analytic signal (unscaled by 1/N)

    // ---- emit phase (fp32) or amplitude (bf16)
    const float inv_n = 1.0f / 4096.0f;
    if (band < N_PHA) {
        float* dst = pha + (bc * N_PHA + band) * T_LEN;
        for (int i = tid; i < 4096; i += 256) {
            const float2 zz = *(const float2*)&z[ZA(i)];
            dst[i] = atan2f(zz.y, zz.x);         // scale cancels in atan2
        }
    } else {
        unsigned short* dst = amp_bf + (bc * N_AMP + (band - N_PHA)) * T_LEN;
        for (int i = tid; i < 4096; i += 256) {
            const float2 zz = *(const float2*)&z[ZA(i)];
            dst[i] = f2bf(sqrtf(zz.x * zz.x + zz.y * zz.y) * inv_n);
        }
    }
}

// ---------------------------------------------------------------------------
// Kernel 2: per (bc, pha-band): 3-hot soft phase binning + einsum via MFMA.
// Phase loads hoisted to kernel start; A-fragments prefetched before the
// softmax so global latency overlaps compute.
// ---------------------------------------------------------------------------
__global__ __launch_bounds__(256) void bin_mi_mfma(
    const float* __restrict__ pha,             // (BC, 10, T) fp32
    const unsigned short* __restrict__ amp_bf, // (BC, 10, T) bf16 bits
    float* __restrict__ out)                   // (BC, 10, 10)
{
    const int tid  = threadIdx.x;
    const int lane = tid & 63;
    const int wv   = tid >> 6;        // 0..3
    const int bc   = blockIdx.x / N_PHA;
    const int p    = blockIdx.x % N_PHA;

    __shared__ unsigned int wbufW[4][18 * 68];  // per-wave, 128 samples + pad
    __shared__ float psum[4][11][N_BINS];
    __shared__ float asum[11][N_BINS];

    const float* phrow = pha + (bc * N_PHA + p) * T_LEN;
    const unsigned short* arow = amp_bf + bc * N_AMP * T_LEN;

    const float PI_F  = 3.14159274101257324f;
    const float INVD  = 2.8647889756541160f;   // 9/pi
    const float DELTA = 0.34906585039886590f;  // 2pi/18
    const float C1    = 12.184696791468343f;   // DELTA^2 / 0.01
    const float C2    = 69.813170079773180f;   // 2*DELTA / 0.01

    const int m_ = lane & 15;
    const int q_ = lane >> 4;
    const int n_ = lane & 15;

    short8 zero8;
#pragma unroll
    for (int j = 0; j < 8; ++j) zero8[j] = 0;
    short8 ones8;
#pragma unroll
    for (int j = 0; j < 8; ++j) ones8[j] = (short)0x3F80;   // bf16 1.0

    f32x4 acc0 = {0.f, 0.f, 0.f, 0.f};   // bins 0..15
    f32x4 acc1 = {0.f, 0.f, 0.f, 0.f};   // bins 16..17

    const int base_t = wv * 1024;
    unsigned short* wh = (unsigned short*)&wbufW[wv][0];

    // hoist all phase loads (issue early, independent)
    float2 pp[8];
#pragma unroll
    for (int c = 0; c < 8; ++c)
        pp[c] = *(const float2*)&phrow[base_t + c * 128 + lane * 2];

    for (int chunk = 0; chunk < 8; ++chunk) {
        const int cb = base_t + chunk * 128;

        // prefetch this chunk's A fragments (latency overlaps softmax below)
        short8 af[4];
#pragma unroll
        for (int s = 0; s < 4; ++s) {
            const int tA = cb + s * 32 + q_ * 8;
            if (m_ < N_AMP)       af[s] = *(const short8*)(arow + m_ * T_LEN + tA);
            else if (m_ == N_AMP) af[s] = ones8;
            else                  af[s] = zero8;
        }

        // zero this lane's column in all 18 rows
#pragma unroll
        for (int k = 0; k < N_BINS; ++k)
            wbufW[wv][k * 68 + lane] = 0u;

        // 3-hot softmax, two samples
#pragma unroll
        for (int h = 0; h < 2; ++h) {
            const float ph = h ? pp[chunk].y : pp[chunk].x;
            float u  = (ph + PI_F) * INVD;       // in [0, 18]
            float jf = floorf(u);
            float d  = (u - jf - 0.5f) * DELTA;
            int j0 = (int)jf;
            if (j0 >= N_BINS) j0 -= N_BINS;      // ph == +pi wraps
            const int jm = (j0 == 0) ? N_BINS - 1 : j0 - 1;
            const int jp = (j0 == N_BINS - 1) ? 0 : j0 + 1;
            const float em = expf(-C1 - C2 * d);
            const float ep = expf(-C1 + C2 * d);
            const float inv = 1.0f / (1.0f + em + ep);
            wh[(j0 * 68 + lane) * 2 + h] = f2bf(inv);
            wh[(jm * 68 + lane) * 2 + h] = f2bf(em * inv);
            wh[(jp * 68 + lane) * 2 + h] = f2bf(ep * inv);
        }
        __builtin_amdgcn_wave_barrier();   // pin: w stores before frag reads

        // ---- 4 MFMA K-steps (K=32 each)
#pragma unroll
        for (int s = 0; s < 4; ++s) {
            const int woff = s * 16 + q_ * 4;
            short8 bfrag0 = *(const short8*)&wbufW[wv][n_ * 68 + woff];
            short8 bfrag1 = (n_ < 2)
                ? *(const short8*)&wbufW[wv][(16 + n_) * 68 + woff]
                : zero8;
            acc0 = __builtin_amdgcn_mfma_f32_16x16x32_bf16(af[s], bfrag0, acc0, 0, 0, 0);
            acc1 = __builtin_amdgcn_mfma_f32_16x16x32_bf16(af[s], bfrag1, acc1, 0, 0, 0);
        }
        __builtin_amdgcn_wave_barrier();   // pin: frag reads before next zeroing
    }

    // ---- per-wave C tiles (C/D: col=lane&15, row=(lane>>4)*4+reg)
#pragma unroll
    for (int r = 0; r < 4; ++r) {
        const int m = q_ * 4 + r;
        if (m < 11) {
            psum[wv][m][n_] = acc0[r];
            if (n_ < 2) psum[wv][m][16 + n_] = acc1[r];
        }
    }
    __syncthreads();

    if (tid < 11 * N_BINS) {
        const int m = tid / N_BINS;
        const int k = tid % N_BINS;
        asum[m][k] = psum[0][m][k] + psum[1][m][k] + psum[2][m][k] + psum[3][m][k];
    }
    __syncthreads();

    if (tid < N_AMP) {
        float ma[N_BINS];
        float msum = 0.0f;
#pragma unroll
        for (int k = 0; k < N_BINS; ++k) {
            float m = asum[tid][k] / (asum[10][k] + 1e-8f);
            ma[k] = m;
            msum += m;
        }
        const float inv = 1.0f / (msum + 1e-8f);
        float acc = 0.0f;
#pragma unroll
        for (int k = 0; k < N_BINS; ++k) {
            float pk = ma[k] * inv;
            acc = fmaf(pk, logf(pk + 1e-8f), acc);
        }
        const float logk = 2.89037175789124f;    // log(18)
        out[(bc * N_PHA + p) * N_AMP + tid] = (logk + acc) / logk;
    }
}

extern "C" void kernel_launch(void* const* d_in, const int* in_sizes, int n_in,
                              void* d_out, int out_size, void* d_ws, size_t ws_size,
                              hipStream_t stream) {
    const float* x    = (const float*)d_in[0];   // (4,16,4096) f32
    const float* filt = (const float*)d_in[1];   // (20,513) f32
    float* out = (float*)d_out;                  // (4,16,10,10) f32

    // ws layout: pha fp32 | amp bf16 | Xspec | Hspec  (~18.5 MB total)
    float* pha = (float*)d_ws;                               // BC*10*T fp32
    unsigned short* amp_bf = (unsigned short*)(pha + BC * N_PHA * T_LEN);
    float2* Xs = (float2*)(amp_bf + BC * N_AMP * T_LEN);     // BC*4096 cplx
    float2* Hs = Xs + BC * 4096;                             // 20*4096 cplx

    spectral_pre <<<BC + N_BANDS, 256, 0, stream>>>(x, filt, Xs, Hs);
    spectral_main<<<BC * N_BANDS, 256, 0, stream>>>(x, filt, Xs, Hs, pha, amp_bf);
    bin_mi_mfma  <<<BC * N_PHA,   256, 0, stream>>>(pha, amp_bf, out);
}